// Round 5
// baseline (417.135 us; speedup 1.0000x reference)
//
#include <hip/hip_runtime.h>
#include <cstdint>

typedef __attribute__((ext_vector_type(4))) float f32x4;
typedef __attribute__((ext_vector_type(16))) float f32x16;
typedef __attribute__((ext_vector_type(8))) __bf16 bf16x8;
typedef __attribute__((ext_vector_type(4))) unsigned short u16x4;
typedef __attribute__((ext_vector_type(2))) unsigned int u32x2;
typedef __attribute__((ext_vector_type(4))) float fvec4;

#define DEV __device__ __forceinline__
#define MFMA16(a, b, c) __builtin_amdgcn_mfma_f32_16x16x32_bf16((a), (b), (c), 0, 0, 0)
#define MFMA32(a, b, c) __builtin_amdgcn_mfma_f32_32x32x16_bf16((a), (b), (c), 0, 0, 0)

// RNE float -> bf16
DEV unsigned short f2bf(float f) {
  union { float f; uint32_t u; } c; c.f = f;
  uint32_t u = c.u;
  return (unsigned short)((u + 0x7FFFu + ((u >> 16) & 1u)) >> 16);
}

// pack two floats to 2 bf16 in one dword (round-half-up, 3 VALU ops)
DEV unsigned int pack2(float lo, float hi) {
  union { float f; uint32_t u; } a, b;
  a.f = lo; b.f = hi;
  return __builtin_amdgcn_perm(b.u + 0x8000u, a.u + 0x8000u, 0x07060302u);
}

// async global->LDS, 16B/lane; LDS dest = wave-uniform base + lane*16
DEV void gll16(const void* g, void* l) {
  __builtin_amdgcn_global_load_lds(
      (const __attribute__((address_space(1))) void*)(uintptr_t)g,
      (__attribute__((address_space(3))) void*)(uint32_t)(uintptr_t)l,
      16, 0, 0);
}

// ---------------- fused prologue: hs fp32->bf16 (z=4) + 4x W transpose (z<4) ----
__global__ void prologue(const float* __restrict__ hs, unsigned short* __restrict__ hsb,
                         const float* __restrict__ W0, const float* __restrict__ W1,
                         const float* __restrict__ W2, const float* __restrict__ W3,
                         unsigned short* __restrict__ Dqkv, unsigned short* __restrict__ Do) {
  const int tid = threadIdx.y * 32 + threadIdx.x;
  if (blockIdx.z == 4) {  // cvt: 4096 blocks x 256 thr x 8 elems
    const int id = blockIdx.y * 64 + blockIdx.x;
    int i = (id * 256 + tid) * 8;
    #pragma unroll
    for (int u = 0; u < 2; ++u) {
      fvec4 v = *(const fvec4*)(hs + i + u * 4);
      u16x4 o;
      o[0] = f2bf(v[0]); o[1] = f2bf(v[1]); o[2] = f2bf(v[2]); o[3] = f2bf(v[3]);
      *(u16x4*)(hsb + i + u * 4) = o;
    }
    return;
  }
  __shared__ float t[32][33];
  const float* W = blockIdx.z == 0 ? W0 : blockIdx.z == 1 ? W1 : blockIdx.z == 2 ? W2 : W3;
  unsigned short* WT = blockIdx.z < 3 ? Dqkv + (size_t)blockIdx.z * 2048 * 2048 : Do;
  int n0 = blockIdx.x * 32, k0 = blockIdx.y * 32;
  int x = threadIdx.x, y = threadIdx.y;  // block (32,8)
  #pragma unroll
  for (int i = 0; i < 32; i += 8)
    t[y + i][x] = W[(size_t)(k0 + y + i) * 2048 + n0 + x];
  __syncthreads();
  #pragma unroll
  for (int i = 0; i < 32; i += 8)
    WT[(size_t)(n0 + y + i) * 2048 + k0 + x] = f2bf(t[x][y + i]);
}

// softmax scale folded into Q (exp2 domain): rsqrt(DH)*log2(e)
constexpr float QSC = 0.08838834764831845f * 1.4426950408889634f;

// ---------------- 128x128-tile GEMM, flat grid + XCD swizzle ----------------
// MODE 0: C = A@Bt^T + b0 -> fp32 o0 [4096][2048]
// MODE 1: fused QKV (N=6144): Q (scaled QSC)/K -> [bh][s][d] bf16; V -> Vt[bh][d][s]
template <int MODE>
__global__ __launch_bounds__(256, 2) void gemm128(
    const unsigned short* __restrict__ A,
    const unsigned short* __restrict__ Bt,
    const float* __restrict__ b0, const float* __restrict__ b1,
    const float* __restrict__ b2,
    void* __restrict__ o0, void* __restrict__ o1, void* __restrict__ o2) {
  __shared__ unsigned short As[128 * 64];
  __shared__ unsigned short Bs[128 * 64];
  const int id = blockIdx.x;
  const int m0 = (((id & 7) << 2) | ((id >> 3) & 3)) * 128;
  const int n0 = (id >> 5) * 128;
  const int tid = threadIdx.x;
  const int wave = tid >> 6, lid = tid & 63;
  const int l16 = lid & 15, lq = lid >> 4;
  const int wm = (wave >> 1) * 64, wn = (wave & 1) * 64;

  const int srow = lid >> 3;
  const int sgrp = (lid & 7) ^ srow;

  f32x4 acc[4][4] = {};

  for (int k0 = 0; k0 < 2048; k0 += 64) {
    #pragma unroll
    for (int i = 0; i < 4; ++i) {
      const int t = wave * 4 + i;
      const int r = t * 8 + srow;
      gll16(A + (size_t)(m0 + r) * 2048 + k0 + sgrp * 8, (char*)As + t * 1024 + lid * 16);
      gll16(Bt + (size_t)(n0 + r) * 2048 + k0 + sgrp * 8, (char*)Bs + t * 1024 + lid * 16);
    }
    __syncthreads();
    #pragma unroll
    for (int kk = 0; kk < 2; ++kk) {
      const int G = kk * 4 + lq;
      bf16x8 af[4], bfr[4];
      #pragma unroll
      for (int i = 0; i < 4; ++i)
        af[i] = *(const bf16x8*)(As + (wm + i * 16 + l16) * 64 + ((G ^ (l16 & 7)) << 3));
      #pragma unroll
      for (int j = 0; j < 4; ++j)
        bfr[j] = *(const bf16x8*)(Bs + (wn + j * 16 + l16) * 64 + ((G ^ (l16 & 7)) << 3));
      #pragma unroll
      for (int i = 0; i < 4; ++i)
        #pragma unroll
        for (int j = 0; j < 4; ++j)
          acc[i][j] = MFMA16(af[i], bfr[j], acc[i][j]);
    }
    __syncthreads();
  }

  #pragma unroll
  for (int j = 0; j < 4; ++j) {
    const int c = n0 + wn + j * 16 + l16;
    if (MODE == 1) {
      const int which = c >> 11;  // 0=Q 1=K 2=V
      const int hd = c & 2047;
      const int h = hd >> 7, d = hd & 127;
      const float* bp = which == 0 ? b0 : which == 1 ? b1 : b2;
      const float bv = bp[hd];
      if (which == 2) {
        #pragma unroll
        for (int i = 0; i < 4; ++i) {
          const int row0 = m0 + wm + i * 16 + lq * 4;
          const int bb = row0 >> 11, s0 = row0 & 2047;
          u16x4 pv;
          #pragma unroll
          for (int r = 0; r < 4; ++r) pv[r] = f2bf(acc[i][j][r] + bv);
          *(u16x4*)((unsigned short*)o2 + ((size_t)((bb * 16 + h) * 128 + d)) * 2048 + s0) = pv;
        }
      } else {
        const float sc = which == 0 ? QSC : 1.0f;
        unsigned short* op = which == 0 ? (unsigned short*)o0 : (unsigned short*)o1;
        #pragma unroll
        for (int i = 0; i < 4; ++i) {
          #pragma unroll
          for (int r = 0; r < 4; ++r) {
            const int row = m0 + wm + i * 16 + lq * 4 + r;
            const int bb = row >> 11, s = row & 2047;
            op[(size_t)((bb * 16 + h) * 2048 + s) * 128 + d] = f2bf((acc[i][j][r] + bv) * sc);
          }
        }
      }
    } else {
      const float bv = b0[c];
      #pragma unroll
      for (int i = 0; i < 4; ++i)
        #pragma unroll
        for (int r = 0; r < 4; ++r) {
          const int row = m0 + wm + i * 16 + lq * 4 + r;
          ((float*)o0)[(size_t)row * 2048 + c] = acc[i][j][r] + bv;
        }
    }
  }
}

// ---------------- flash attention: 64-q blocks, P kept in registers ----------------
// grid (32,32), 128 thr (2 waves, 32 q each). jq = (bh&8)? x : 31-x  -> the 4
// blocks sharing a CU (id, id+256, id+512, id+768) sum to 66 tile-units.
// P transform C-layout -> B-operand done in-register: 1 shfl_xor(32) per k16.
__global__ __launch_bounds__(128, 2) void attn(
    const unsigned short* __restrict__ Q,
    const unsigned short* __restrict__ K,
    const unsigned short* __restrict__ Vt,
    unsigned short* __restrict__ ctx) {
  __shared__ unsigned short Ks[64 * 128];   // [kr][16B-chunk ^ (kr&15)] 16KB
  __shared__ unsigned short Vts[128 * 64];  // [d][16B-chunk ^ (d&7)]    16KB

  const int bh = blockIdx.y;
  const int jq = (bh & 8) ? (int)blockIdx.x : 31 - (int)blockIdx.x;
  const int q0 = jq * 64;
  const int b = bh >> 4, h = bh & 15;
  const unsigned short* Qh = Q + (size_t)bh * 2048 * 128;
  const unsigned short* Kh = K + (size_t)bh * 2048 * 128;
  const unsigned short* Vth = Vt + (size_t)bh * 128 * 2048;

  const int tid = threadIdx.x;
  const int wave = tid >> 6, lid = tid & 63;
  const int l32 = lid & 31, half = lid >> 5;
  const int qrow = q0 + wave * 32 + l32;

  // Q fragments (B-operand): B[k=d][n=q]
  bf16x8 qf[8];
  #pragma unroll
  for (int ds = 0; ds < 8; ++ds)
    qf[ds] = *(const bf16x8*)(Qh + (size_t)qrow * 128 + ds * 16 + half * 8);

  float m_i = -1e30f, l_i = 0.f;
  f32x16 acc[4] = {};  // O^T: acc[db], d = db*32 + (reg&3)+8*(reg>>2)+4*half, col=q

  for (int jt = 0; jt <= jq; ++jt) {
    const int k0 = jt * 64;
    #pragma unroll
    for (int ii = 0; ii < 8; ++ii) {  // K tile 16KB: 2 waves x 8 calls
      const int t = wave * 8 + ii;
      const int r = t * 4 + (lid >> 4);
      const int g = (lid & 15) ^ (r & 15);
      gll16(Kh + (size_t)(k0 + r) * 128 + g * 8, (char*)Ks + t * 1024 + lid * 16);
    }
    #pragma unroll
    for (int ii = 0; ii < 8; ++ii) {  // Vt tile 16KB
      const int t = wave * 8 + ii;
      const int d = t * 8 + (lid >> 3);
      const int g = (lid & 7) ^ (d & 7);
      gll16(Vth + (size_t)d * 2048 + k0 + g * 8, (char*)Vts + t * 1024 + lid * 16);
    }
    __syncthreads();

    // S^T = K Q^T: A=K-frag (m=k-row), B=Q-frag (n=q)
    f32x16 sacc[2] = {};
    #pragma unroll
    for (int ds = 0; ds < 8; ++ds) {
      #pragma unroll
      for (int mb = 0; mb < 2; ++mb) {
        const int kr = mb * 32 + l32;
        bf16x8 af = *(const bf16x8*)(Ks + kr * 128 + (((ds * 2 + half) ^ (kr & 15)) << 3));
        sacc[mb] = MFMA32(af, qf[ds], sacc[mb]);
      }
    }

    if (jt == jq) {  // diagonal tile: causal mask
      #pragma unroll
      for (int mb = 0; mb < 2; ++mb)
        #pragma unroll
        for (int i = 0; i < 16; ++i) {
          const int kg = k0 + mb * 32 + (i & 3) + 8 * (i >> 2) + 4 * half;
          if (kg > qrow) sacc[mb][i] = -1e30f;
        }
    }

    float tmax = -1e30f;
    #pragma unroll
    for (int mb = 0; mb < 2; ++mb)
      #pragma unroll
      for (int i = 0; i < 16; ++i) tmax = fmaxf(tmax, sacc[mb][i]);
    tmax = fmaxf(tmax, __shfl_xor(tmax, 32));

    const float mnew = fmaxf(m_i, tmax);
    const float alpha = exp2f(m_i - mnew);
    m_i = mnew;
    #pragma unroll
    for (int db = 0; db < 4; ++db)
      #pragma unroll
      for (int i = 0; i < 16; ++i) acc[db][i] *= alpha;

    // exp + pack: pk[mb][u] covers k' = mb*32 + 8u + 4*half + {0..3}
    float ps = 0.f;
    u32x2 pk[2][4];
    #pragma unroll
    for (int mb = 0; mb < 2; ++mb) {
      #pragma unroll
      for (int i = 0; i < 16; ++i) {
        sacc[mb][i] = exp2f(sacc[mb][i] - mnew);
        ps += sacc[mb][i];
      }
      #pragma unroll
      for (int u = 0; u < 4; ++u) {
        pk[mb][u][0] = pack2(sacc[mb][4 * u], sacc[mb][4 * u + 1]);
        pk[mb][u][1] = pack2(sacc[mb][4 * u + 2], sacc[mb][4 * u + 3]);
      }
    }
    ps += __shfl_xor(ps, 32);
    l_i = l_i * alpha + ps;

    // O^T += V^T P^T, P fragments built in-register (no LDS round-trip).
    // B-frag for k-group g needs lane(h,q): k = 16g+8h+j. Exchange one u32x2
    // across half-waves: h=0 sends pk[u0+1], h=1 sends pk[u0].
    #pragma unroll
    for (int g = 0; g < 4; ++g) {
      const int mb = g >> 1, u0 = (g & 1) * 2;
      u32x2 vx, own;
      vx[0] = half ? pk[mb][u0][0] : pk[mb][u0 + 1][0];
      vx[1] = half ? pk[mb][u0][1] : pk[mb][u0 + 1][1];
      own[0] = half ? pk[mb][u0 + 1][0] : pk[mb][u0][0];
      own[1] = half ? pk[mb][u0 + 1][1] : pk[mb][u0][1];
      u32x2 r;
      r[0] = __shfl_xor((unsigned int)vx[0], 32);
      r[1] = __shfl_xor((unsigned int)vx[1], 32);
      union { unsigned int u[4]; bf16x8 v; } pf;
      pf.u[0] = half ? r[0] : own[0];
      pf.u[1] = half ? r[1] : own[1];
      pf.u[2] = half ? own[0] : r[0];
      pf.u[3] = half ? own[1] : r[1];
      #pragma unroll
      for (int db = 0; db < 4; ++db) {
        const int d = db * 32 + l32;
        bf16x8 vf = *(const bf16x8*)(Vts + d * 64 + (((g * 2 + half) ^ (d & 7)) << 3));
        acc[db] = MFMA32(vf, pf.v, acc[db]);
      }
    }
    __syncthreads();
  }

  // epilogue: ctx[b][s][h*128+d], packed 8B stores
  const float inv = 1.f / l_i;
  const size_t base = ((size_t)(b * 2048 + qrow)) * 2048 + h * 128;
  #pragma unroll
  for (int db = 0; db < 4; ++db) {
    #pragma unroll
    for (int u = 0; u < 4; ++u) {
      u32x2 w;
      w[0] = pack2(acc[db][4 * u] * inv, acc[db][4 * u + 1] * inv);
      w[1] = pack2(acc[db][4 * u + 2] * inv, acc[db][4 * u + 3] * inv);
      *(u32x2*)(ctx + base + db * 32 + 8 * u + 4 * half) = w;
    }
  }
}

// ---------------- launch ----------------
extern "C" void kernel_launch(void* const* d_in, const int* in_sizes, int n_in,
                              void* d_out, int out_size, void* d_ws, size_t ws_size,
                              hipStream_t stream) {
  const float* hs = (const float*)d_in[0];
  const float* Wq = (const float*)d_in[1];
  const float* bq = (const float*)d_in[2];
  const float* Wk = (const float*)d_in[3];
  const float* bk = (const float*)d_in[4];
  const float* Wv = (const float*)d_in[5];
  const float* bv = (const float*)d_in[6];
  const float* Wo = (const float*)d_in[7];
  const float* bo = (const float*)d_in[8];
  // d_in[9] = causal_mask (standard causal; computed analytically in attn)
  float* out = (float*)d_out;

  char* ws = (char*)d_ws;
  unsigned short* hsb   = (unsigned short*)(ws);              // 16 MB [4096][2048]
  unsigned short* wqkvt = (unsigned short*)(ws + (16 << 20)); // 24 MB [6144][2048]
  unsigned short* wot   = (unsigned short*)(ws + (40 << 20)); //  8 MB
  unsigned short* Qb    = (unsigned short*)(ws + (48 << 20)); // 16 MB [bh][s][d]
  unsigned short* Kb    = (unsigned short*)(ws + (64 << 20)); // 16 MB [bh][s][d]
  unsigned short* Vtb   = (unsigned short*)(ws + (80 << 20)); // 16 MB [bh][d][s]
  unsigned short* ctx   = (unsigned short*)(ws + (96 << 20)); // 16 MB [4096][2048]

  prologue<<<dim3(64, 64, 5), dim3(32, 8), 0, stream>>>(hs, hsb, Wq, Wk, Wv, Wo, wqkvt, wot);

  gemm128<1><<<dim3(1536), 256, 0, stream>>>(hsb, wqkvt, bq, bk, bv,
                                             (void*)Qb, (void*)Kb, (void*)Vtb);
  attn<<<dim3(32, 32), 128, 0, stream>>>(Qb, Kb, Vtb, ctx);
  gemm128<0><<<dim3(512), 256, 0, stream>>>(ctx, wot, bo, nullptr, nullptr,
                                            (void*)out, nullptr, nullptr);
}